// Round 3
// baseline (1658.825 us; speedup 1.0000x reference)
//
#include <hip/hip_runtime.h>
#include <cmath>

// AdaptiveMetaLearnerV1: B=64, P=4096, H=40, L=2, two LSTM branches.
// Strategy: wave-quadrant decomposition. Block=256 (4 waves); wave q owns
// h-slots [q*10, q*10+10) for all 4 gates; lanes = 64 consecutive positions.
// Weight addresses are wave-uniform -> s_load (SGPR broadcast), so the three
// 40x160 matvecs per position run as pure v_fmac with SGPR operands.
// Layer-0 ih is affine in scalar x: ih0[j] = x*A[j] + C[j] (A,C precomputed
// per block into LDS). Cross-quadrant LN stats / h exchange / output dot via
// small LDS buffers + barriers (all wave-uniform control flow).
//
// R1: tanh must be RELATIVE-accurate (LN with var<<eps amplifies absolute
// error by rsqrt(1e-5)=316, twice) -> libm tanhf.
// R2: R1 profile showed WRITE_SIZE=206MB (expected ~1MB) at VGPR_Count=128:
// the allocator targeted 4 waves/EU and spilled ~50 regs/lane in the hot
// loop (live state: pre_i[40]+pre_h[40]+input[40] ~ 170 VGPR demand).
// Force waves_per_eu(2,2) so the allocator may use up to 256 VGPRs -> no
// spills at 8 waves/CU.

#define NB 64
#define NP 4096
#define NBP (NB * NP)
#define LN_EPS 1e-5f

struct PtrPack { const float* p[34]; };

__device__ __forceinline__ float rcp_f(float x) { return __builtin_amdgcn_rcpf(x); }
__device__ __forceinline__ float rsq_f(float x) { return __builtin_amdgcn_rsqf(x); }
__device__ __forceinline__ float sigm(float x)  { return rcp_f(1.0f + __expf(-x)); }

struct F40 { float v[40]; };

__device__ __forceinline__ void load_row16(const float* __restrict__ src, F40& r) {
    #pragma unroll
    for (int k4 = 0; k4 < 10; ++k4) {
        float4 t = reinterpret_cast<const float4*>(src)[k4];
        r.v[k4*4+0] = t.x; r.v[k4*4+1] = t.y; r.v[k4*4+2] = t.z; r.v[k4*4+3] = t.w;
    }
}

// pre[g][u] = bias[j] + sum_k in[k]*W[j*40+k], j = g*40 + q10 + u  (j uniform)
__device__ __forceinline__ void matvec(const float* __restrict__ W, const float* __restrict__ bias,
                                       const F40& in, int q10, float pre[4][10],
                                       float& s1, float& s2) {
    s1 = 0.0f; s2 = 0.0f;
    #pragma unroll
    for (int g = 0; g < 4; ++g) {
        #pragma unroll
        for (int u = 0; u < 10; ++u) {
            const int j = g*40 + q10 + u;
            const float* __restrict__ wr = W + j*40;
            float acc = bias[j];
            #pragma unroll
            for (int k = 0; k < 40; ++k) acc = fmaf(in.v[k], wr[k], acc);
            pre[g][u] = acc;
            s1 += acc;
            s2 = fmaf(acc, acc, s2);
        }
    }
}

__global__ __launch_bounds__(256)
__attribute__((amdgpu_waves_per_eu(2, 2)))
void aml_fwd(PtrPack P, float* __restrict__ out, int iters)
{
    const int br = blockIdx.y;            // 0: main branch, 1: 'a_' branch
    const int pb = 6 + 14*br;
    const float* __restrict__ xin  = P.p[0];
    const float* __restrict__ hxg  = P.p[1 + 2*br];   // hx / act_hx
    const float* __restrict__ cxg  = P.p[2 + 2*br];   // cx / act_cx
    const float* __restrict__ W1   = P.p[pb+0];
    const float* __restrict__ b1   = P.p[pb+1];
    const float* __restrict__ Wo   = P.p[pb+2];
    const float* __restrict__ bo   = P.p[pb+3];
    const float* __restrict__ Wih  = P.p[pb+4];       // [2][160][40]
    const float* __restrict__ Whh  = P.p[pb+5];
    const float* __restrict__ bih  = P.p[pb+6];       // [2][160]
    const float* __restrict__ bhh  = P.p[pb+7];
    const float* __restrict__ gih  = P.p[pb+8];
    const float* __restrict__ bihn = P.p[pb+9];
    const float* __restrict__ ghh  = P.p[pb+10];
    const float* __restrict__ bhhn = P.p[pb+11];
    const float* __restrict__ gcv  = P.p[pb+12];      // [2][40]
    const float* __restrict__ bcv  = P.p[pb+13];
    const float lam4096 = P.p[5][0] * (1.0f / 4096.0f);

    __shared__ float sA[160], sC[160];
    __shared__ float redA[4][4][64];
    __shared__ float redB[4][2][64];
    __shared__ float redO[4][64];
    __shared__ float hX[64 * 41];         // stride 41: conflict-free row reads

    const int tid = threadIdx.x;
    const int wq  = __builtin_amdgcn_readfirstlane(tid >> 6);  // quadrant, SGPR
    const int lp  = tid & 63;                                   // position lane
    const int q10 = wq * 10;

    // Layer-0 ih affine precompute: A = Wih0 @ W1, C = Wih0 @ b1 + bih0
    if (tid < 160) {
        float a = 0.0f, c = 0.0f;
        const float* wr = Wih + tid*40;
        #pragma unroll
        for (int k = 0; k < 40; ++k) { a = fmaf(wr[k], W1[k], a); c = fmaf(wr[k], b1[k], c); }
        sA[tid] = a; sC[tid] = c + bih[tid];
    }
    __syncthreads();

    float pre_i[4][10], pre_h[4][10], hval[10];

    // gates -> c -> LN(c) -> h  (shared between layers; one barrier inside)
    auto tail = [&](int l, float mi, float ri, float mh, float rh, int pos) {
        const int lb = l * 160;
        float gate[4][10];
        #pragma unroll
        for (int g = 0; g < 4; ++g)
            #pragma unroll
            for (int u = 0; u < 10; ++u) {
                const int jj = lb + g*40 + q10 + u;
                gate[g][u] = fmaf((pre_i[g][u] - mi) * ri, gih[jj], bihn[jj])
                           + fmaf((pre_h[g][u] - mh) * rh, ghh[jj], bhhn[jj]);
            }
        float cin[10];
        const float* crow = cxg + (size_t)(l*NBP + pos)*40 + q10;
        #pragma unroll
        for (int u2 = 0; u2 < 5; ++u2) {
            float2 t = reinterpret_cast<const float2*>(crow)[u2];
            cin[2*u2] = t.x; cin[2*u2+1] = t.y;
        }
        float cc[10], s1c = 0.0f, s2c = 0.0f;
        #pragma unroll
        for (int u = 0; u < 10; ++u) {
            float cv = sigm(gate[1][u] + 1.0f) * cin[u] + sigm(gate[0][u]) * tanhf(gate[2][u]);
            cc[u] = cv; s1c += cv; s2c = fmaf(cv, cv, s2c);
        }
        redB[wq][0][lp] = s1c; redB[wq][1][lp] = s2c;
        __syncthreads();
        float S1c = 0.0f, S2c = 0.0f;
        #pragma unroll
        for (int qq = 0; qq < 4; ++qq) { S1c += redB[qq][0][lp]; S2c += redB[qq][1][lp]; }
        const float mc = S1c * (1.0f/40.0f);
        const float vc = fmaf(-mc, mc, S2c * (1.0f/40.0f));
        const float rc = rsq_f(vc + LN_EPS);
        #pragma unroll
        for (int u = 0; u < 10; ++u) {
            const float cn = fmaf((cc[u] - mc) * rc, gcv[l*40 + q10 + u], bcv[l*40 + q10 + u]);
            hval[u] = sigm(gate[3][u]) * tanhf(cn);
        }
    };

    #pragma unroll 1
    for (int it = 0; it < iters; ++it) {
        const int pos = (blockIdx.x * iters + it) * 64 + lp;

        // ---------------- layer 0 ----------------
        const float xv = xin[pos];
        float s1i = 0.0f, s2i = 0.0f;
        #pragma unroll
        for (int g = 0; g < 4; ++g)
            #pragma unroll
            for (int u = 0; u < 10; ++u) {
                const int j = g*40 + q10 + u;
                const float v = fmaf(xv, sA[j], sC[j]);
                pre_i[g][u] = v; s1i += v; s2i = fmaf(v, v, s2i);
            }
        F40 inr;
        load_row16(hxg + (size_t)pos * 40, inr);
        float s1h, s2h;
        matvec(Whh, bhh, inr, q10, pre_h, s1h, s2h);

        redA[wq][0][lp] = s1i; redA[wq][1][lp] = s2i;
        redA[wq][2][lp] = s1h; redA[wq][3][lp] = s2h;
        __syncthreads();
        {
            float S1i=0, S2i=0, S1h=0, S2h=0;
            #pragma unroll
            for (int qq = 0; qq < 4; ++qq) {
                S1i += redA[qq][0][lp]; S2i += redA[qq][1][lp];
                S1h += redA[qq][2][lp]; S2h += redA[qq][3][lp];
            }
            const float mi = S1i*(1.0f/160.0f), vi = fmaf(-mi, mi, S2i*(1.0f/160.0f));
            const float mh = S1h*(1.0f/160.0f), vh = fmaf(-mh, mh, S2h*(1.0f/160.0f));
            tail(0, mi, rsq_f(vi + LN_EPS), mh, rsq_f(vh + LN_EPS), pos);
        }

        // h exchange (cross-wave): full 40-vector per position
        #pragma unroll
        for (int u = 0; u < 10; ++u) hX[lp*41 + q10 + u] = hval[u];
        __syncthreads();
        F40 inh;
        #pragma unroll
        for (int k = 0; k < 40; ++k) inh.v[k] = hX[lp*41 + k];

        // ---------------- layer 1 ----------------
        float s1i1, s2i1, s1h1, s2h1;
        matvec(Wih + 160*40, bih + 160, inh, q10, pre_i, s1i1, s2i1);
        load_row16(hxg + (size_t)(NBP + pos) * 40, inr);
        matvec(Whh + 160*40, bhh + 160, inr, q10, pre_h, s1h1, s2h1);

        redA[wq][0][lp] = s1i1; redA[wq][1][lp] = s2i1;
        redA[wq][2][lp] = s1h1; redA[wq][3][lp] = s2h1;
        __syncthreads();
        {
            float S1i=0, S2i=0, S1h=0, S2h=0;
            #pragma unroll
            for (int qq = 0; qq < 4; ++qq) {
                S1i += redA[qq][0][lp]; S2i += redA[qq][1][lp];
                S1h += redA[qq][2][lp]; S2h += redA[qq][3][lp];
            }
            const float mi = S1i*(1.0f/160.0f), vi = fmaf(-mi, mi, S2i*(1.0f/160.0f));
            const float mh = S1h*(1.0f/160.0f), vh = fmaf(-mh, mh, S2h*(1.0f/160.0f));
            tail(1, mi, rsq_f(vi + LN_EPS), mh, rsq_f(vh + LN_EPS), pos);
        }

        // ---------------- output ----------------
        float po = 0.0f;
        #pragma unroll
        for (int u = 0; u < 10; ++u) po = fmaf(Wo[q10 + u], hval[u], po);
        redO[wq][lp] = po;
        __syncthreads();
        if (wq == 0) {
            const float o = redO[0][lp] + redO[1][lp] + redO[2][lp] + redO[3][lp] + bo[0];
            if (br == 0) {
                out[pos] = o;                       // x_out
            } else {
                float v = lam4096 * tanhf(o);       // qt contribution
                #pragma unroll
                for (int off = 32; off > 0; off >>= 1) v += __shfl_down(v, off, 64);
                if (lp == 0) atomicAdd(out + NBP + (pos >> 12), v);
            }
        }
    }
}

extern "C" void kernel_launch(void* const* d_in, const int* in_sizes, int n_in,
                              void* d_out, int out_size, void* d_ws, size_t ws_size,
                              hipStream_t stream)
{
    (void)in_sizes; (void)d_ws; (void)ws_size; (void)out_size;
    PtrPack P;
    for (int i = 0; i < 34 && i < n_in; ++i) P.p[i] = (const float*)d_in[i];
    float* out = (float*)d_out;

    // qt_out region accumulated via atomics -> zero it (d_out is poisoned 0xAA)
    hipMemsetAsync(out + NBP, 0, NB * sizeof(float), stream);

    const int iters = 4;                       // 1024 blocks * 4 iters * 64 pos = 262144
    dim3 grid(NBP / (64 * iters), 2), block(256);
    hipLaunchKernelGGL(aml_fwd, grid, block, 0, stream, P, out, iters);
}

// Round 4
// 1554.038 us; speedup vs baseline: 1.0674x; 1.0674x over previous
//
#include <hip/hip_runtime.h>
#include <cmath>

// AdaptiveMetaLearnerV1: B=64, P=4096, H=40, L=2, two LSTM branches.
// Strategy: wave-quadrant decomposition. Block=256 (4 waves); wave q owns
// h-slots [q*10, q*10+10) for all 4 gates; lanes = 64 consecutive positions.
// Weight addresses are wave-uniform -> SGPR broadcast; the matvecs run as
// v_fmac with SGPR operands. Layer-0 ih is affine in scalar x (A,C in LDS).
//
// R1: tanh must be RELATIVE-accurate (LN with var<<eps amplifies absolute
//     error by rsqrt(1e-5)=316, twice).
// R2/R3: 206MB scratch writes with VGPR pinned at 128 even when the
//     allocator had a 256-reg budget (launch_bounds(256,2) AND
//     waves_per_eu(2,2) both ignored) -> NOT pressure spill. Theory: libm
//     tanhf survives as a real __ocml call; call ABI forces caller-saved
//     spills of live state (~25 regs) around ~41 calls/position.
// R4: hand-rolled guaranteed-inline relative-accurate tanh (poly |x|<0.25,
//     exp-form above; branchless). Also recompute layer-0 pre_i in the tail
//     (2 FMAs from LDS) instead of holding 40 regs across the barrier.

#define NB 64
#define NP 4096
#define NBP (NB * NP)
#define LN_EPS 1e-5f

struct PtrPack { const float* p[34]; };

__device__ __forceinline__ float rcp_f(float x) { return __builtin_amdgcn_rcpf(x); }
__device__ __forceinline__ float rsq_f(float x) { return __builtin_amdgcn_rsqf(x); }
__device__ __forceinline__ float sigm(float x)  { return rcp_f(1.0f + __expf(-x)); }

// Relative-accurate tanh, fully inline (no libm call).
// |x| <  0.25: odd Taylor through x^9 -> leading term exact, rel err ~3e-7.
// |x| >= 0.25: 1 - 2/(e^{2|x|}+1): abs err ~1.2e-7 -> rel err <= 5e-7 there.
__device__ __forceinline__ float tanh_rel(float x) {
    const float ax = fabsf(x);
    const float x2 = ax * ax;
    // Taylor: -1/3, 2/15, -17/315, 62/2835
    float p = fmaf(x2, 0.021869488f, -0.053968254f);
    p = fmaf(x2, p, 0.133333333f);
    p = fmaf(x2, p, -0.333333333f);
    const float small = fmaf(ax * x2, p, ax);
    const float e = __expf(2.0f * ax);
    const float big = 1.0f - 2.0f * rcp_f(e + 1.0f);
    const float t = (ax < 0.25f) ? small : big;
    return copysignf(t, x);
}

struct F40 { float v[40]; };

__device__ __forceinline__ void load_row16(const float* __restrict__ src, F40& r) {
    #pragma unroll
    for (int k4 = 0; k4 < 10; ++k4) {
        float4 t = reinterpret_cast<const float4*>(src)[k4];
        r.v[k4*4+0] = t.x; r.v[k4*4+1] = t.y; r.v[k4*4+2] = t.z; r.v[k4*4+3] = t.w;
    }
}

// pre[g][u] = bias[j] + sum_k in[k]*W[j*40+k], j = g*40 + q10 + u  (j uniform)
__device__ __forceinline__ void matvec(const float* __restrict__ W, const float* __restrict__ bias,
                                       const F40& in, int q10, float pre[4][10],
                                       float& s1, float& s2) {
    s1 = 0.0f; s2 = 0.0f;
    #pragma unroll
    for (int g = 0; g < 4; ++g) {
        #pragma unroll
        for (int u = 0; u < 10; ++u) {
            const int j = g*40 + q10 + u;
            const float* __restrict__ wr = W + j*40;
            float acc = bias[j];
            #pragma unroll
            for (int k = 0; k < 40; ++k) acc = fmaf(in.v[k], wr[k], acc);
            pre[g][u] = acc;
            s1 += acc;
            s2 = fmaf(acc, acc, s2);
        }
    }
}

__global__ __launch_bounds__(256)
__attribute__((amdgpu_waves_per_eu(2, 2)))
void aml_fwd(PtrPack P, float* __restrict__ out, int iters)
{
    const int br = blockIdx.y;            // 0: main branch, 1: 'a_' branch
    const int pb = 6 + 14*br;
    const float* __restrict__ xin  = P.p[0];
    const float* __restrict__ hxg  = P.p[1 + 2*br];   // hx / act_hx
    const float* __restrict__ cxg  = P.p[2 + 2*br];   // cx / act_cx
    const float* __restrict__ W1   = P.p[pb+0];
    const float* __restrict__ b1   = P.p[pb+1];
    const float* __restrict__ Wo   = P.p[pb+2];
    const float* __restrict__ bo   = P.p[pb+3];
    const float* __restrict__ Wih  = P.p[pb+4];       // [2][160][40]
    const float* __restrict__ Whh  = P.p[pb+5];
    const float* __restrict__ bih  = P.p[pb+6];       // [2][160]
    const float* __restrict__ bhh  = P.p[pb+7];
    const float* __restrict__ gih  = P.p[pb+8];
    const float* __restrict__ bihn = P.p[pb+9];
    const float* __restrict__ ghh  = P.p[pb+10];
    const float* __restrict__ bhhn = P.p[pb+11];
    const float* __restrict__ gcv  = P.p[pb+12];      // [2][40]
    const float* __restrict__ bcv  = P.p[pb+13];
    const float lam4096 = P.p[5][0] * (1.0f / 4096.0f);

    __shared__ float sA[160], sC[160];
    __shared__ float redA[4][4][64];
    __shared__ float redB[4][2][64];
    __shared__ float redO[4][64];
    __shared__ float hX[64 * 41];         // stride 41: conflict-free row reads

    const int tid = threadIdx.x;
    const int wq  = __builtin_amdgcn_readfirstlane(tid >> 6);  // quadrant, SGPR
    const int lp  = tid & 63;                                   // position lane
    const int q10 = wq * 10;

    // Layer-0 ih affine precompute: A = Wih0 @ W1, C = Wih0 @ b1 + bih0
    if (tid < 160) {
        float a = 0.0f, c = 0.0f;
        const float* wr = Wih + tid*40;
        #pragma unroll
        for (int k = 0; k < 40; ++k) { a = fmaf(wr[k], W1[k], a); c = fmaf(wr[k], b1[k], c); }
        sA[tid] = a; sC[tid] = c + bih[tid];
    }
    __syncthreads();

    float pre_i[4][10], pre_h[4][10], hval[10];

    // gates -> c -> LN(c) -> h  (shared between layers; one barrier inside).
    // l==0: ih pre-activation recomputed from (xv, sA, sC); pre_i unused.
    auto tail = [&](int l, float xv, float mi, float ri, float mh, float rh, int pos) {
        const int lb = l * 160;
        float gate[4][10];
        #pragma unroll
        for (int g = 0; g < 4; ++g)
            #pragma unroll
            for (int u = 0; u < 10; ++u) {
                const int j  = g*40 + q10 + u;
                const int jj = lb + j;
                const float piv = (l == 0) ? fmaf(xv, sA[j], sC[j]) : pre_i[g][u];
                gate[g][u] = fmaf((piv - mi) * ri, gih[jj], bihn[jj])
                           + fmaf((pre_h[g][u] - mh) * rh, ghh[jj], bhhn[jj]);
            }
        float cin[10];
        const float* crow = cxg + (size_t)(l*NBP + pos)*40 + q10;
        #pragma unroll
        for (int u2 = 0; u2 < 5; ++u2) {
            float2 t = reinterpret_cast<const float2*>(crow)[u2];
            cin[2*u2] = t.x; cin[2*u2+1] = t.y;
        }
        float cc[10], s1c = 0.0f, s2c = 0.0f;
        #pragma unroll
        for (int u = 0; u < 10; ++u) {
            float cv = sigm(gate[1][u] + 1.0f) * cin[u] + sigm(gate[0][u]) * tanh_rel(gate[2][u]);
            cc[u] = cv; s1c += cv; s2c = fmaf(cv, cv, s2c);
        }
        redB[wq][0][lp] = s1c; redB[wq][1][lp] = s2c;
        __syncthreads();
        float S1c = 0.0f, S2c = 0.0f;
        #pragma unroll
        for (int qq = 0; qq < 4; ++qq) { S1c += redB[qq][0][lp]; S2c += redB[qq][1][lp]; }
        const float mc = S1c * (1.0f/40.0f);
        const float vc = fmaf(-mc, mc, S2c * (1.0f/40.0f));
        const float rc = rsq_f(vc + LN_EPS);
        #pragma unroll
        for (int u = 0; u < 10; ++u) {
            const float cn = fmaf((cc[u] - mc) * rc, gcv[l*40 + q10 + u], bcv[l*40 + q10 + u]);
            hval[u] = sigm(gate[3][u]) * tanh_rel(cn);
        }
    };

    #pragma unroll 1
    for (int it = 0; it < iters; ++it) {
        const int pos = (blockIdx.x * iters + it) * 64 + lp;

        // ---------------- layer 0 ----------------
        const float xv = xin[pos];
        float s1i = 0.0f, s2i = 0.0f;
        #pragma unroll
        for (int g = 0; g < 4; ++g)
            #pragma unroll
            for (int u = 0; u < 10; ++u) {
                const int j = g*40 + q10 + u;
                const float v = fmaf(xv, sA[j], sC[j]);
                s1i += v; s2i = fmaf(v, v, s2i);       // stats only; recomputed in tail
            }
        F40 inr;
        load_row16(hxg + (size_t)pos * 40, inr);
        float s1h, s2h;
        matvec(Whh, bhh, inr, q10, pre_h, s1h, s2h);

        redA[wq][0][lp] = s1i; redA[wq][1][lp] = s2i;
        redA[wq][2][lp] = s1h; redA[wq][3][lp] = s2h;
        __syncthreads();
        {
            float S1i=0, S2i=0, S1h=0, S2h=0;
            #pragma unroll
            for (int qq = 0; qq < 4; ++qq) {
                S1i += redA[qq][0][lp]; S2i += redA[qq][1][lp];
                S1h += redA[qq][2][lp]; S2h += redA[qq][3][lp];
            }
            const float mi = S1i*(1.0f/160.0f), vi = fmaf(-mi, mi, S2i*(1.0f/160.0f));
            const float mh = S1h*(1.0f/160.0f), vh = fmaf(-mh, mh, S2h*(1.0f/160.0f));
            tail(0, xv, mi, rsq_f(vi + LN_EPS), mh, rsq_f(vh + LN_EPS), pos);
        }

        // h exchange (cross-wave): full 40-vector per position
        #pragma unroll
        for (int u = 0; u < 10; ++u) hX[lp*41 + q10 + u] = hval[u];
        __syncthreads();
        F40 inh;
        #pragma unroll
        for (int k = 0; k < 40; ++k) inh.v[k] = hX[lp*41 + k];

        // ---------------- layer 1 ----------------
        float s1i1, s2i1, s1h1, s2h1;
        matvec(Wih + 160*40, bih + 160, inh, q10, pre_i, s1i1, s2i1);
        load_row16(hxg + (size_t)(NBP + pos) * 40, inr);
        matvec(Whh + 160*40, bhh + 160, inr, q10, pre_h, s1h1, s2h1);

        redA[wq][0][lp] = s1i1; redA[wq][1][lp] = s2i1;
        redA[wq][2][lp] = s1h1; redA[wq][3][lp] = s2h1;
        __syncthreads();
        {
            float S1i=0, S2i=0, S1h=0, S2h=0;
            #pragma unroll
            for (int qq = 0; qq < 4; ++qq) {
                S1i += redA[qq][0][lp]; S2i += redA[qq][1][lp];
                S1h += redA[qq][2][lp]; S2h += redA[qq][3][lp];
            }
            const float mi = S1i*(1.0f/160.0f), vi = fmaf(-mi, mi, S2i*(1.0f/160.0f));
            const float mh = S1h*(1.0f/160.0f), vh = fmaf(-mh, mh, S2h*(1.0f/160.0f));
            tail(1, 0.0f, mi, rsq_f(vi + LN_EPS), mh, rsq_f(vh + LN_EPS), pos);
        }

        // ---------------- output ----------------
        float po = 0.0f;
        #pragma unroll
        for (int u = 0; u < 10; ++u) po = fmaf(Wo[q10 + u], hval[u], po);
        redO[wq][lp] = po;
        __syncthreads();
        if (wq == 0) {
            const float o = redO[0][lp] + redO[1][lp] + redO[2][lp] + redO[3][lp] + bo[0];
            if (br == 0) {
                out[pos] = o;                       // x_out
            } else {
                float v = lam4096 * tanh_rel(o);    // qt contribution
                #pragma unroll
                for (int off = 32; off > 0; off >>= 1) v += __shfl_down(v, off, 64);
                if (lp == 0) atomicAdd(out + NBP + (pos >> 12), v);
            }
        }
    }
}

extern "C" void kernel_launch(void* const* d_in, const int* in_sizes, int n_in,
                              void* d_out, int out_size, void* d_ws, size_t ws_size,
                              hipStream_t stream)
{
    (void)in_sizes; (void)d_ws; (void)ws_size; (void)out_size;
    PtrPack P;
    for (int i = 0; i < 34 && i < n_in; ++i) P.p[i] = (const float*)d_in[i];
    float* out = (float*)d_out;

    // qt_out region accumulated via atomics -> zero it (d_out is poisoned 0xAA)
    hipMemsetAsync(out + NBP, 0, NB * sizeof(float), stream);

    const int iters = 4;                       // 1024 blocks * 4 iters * 64 pos = 262144
    dim3 grid(NBP / (64 * iters), 2), block(256);
    hipLaunchKernelGGL(aml_fwd, grid, block, 0, stream, P, out, iters);
}